// Round 10
// baseline (194.083 us; speedup 1.0000x reference)
//
#include <hip/hip_runtime.h>

// CTC batch loss (keras ctc_batch_cost), B=256, T=512, C=256, U=64.
// One block of 4 waves per batch (256 CUs, 1 block/CU). Wave 0 runs the
// serial forward recurrence (lane l owns extended states 2l and 2l+1;
// lane 63 also owns state 128; linear domain, wave-uniform power-of-2
// rescale every 8 steps -- numerics identical to the verified r3-r9
// kernels, absmax 16.0).
//
// Evidence (r3/r6/r7/r9): four disjoint data-path structures all land at
// 193.3-194.5 us => kernel ~37us, a memory-THROUGHPUT cap: 512KB/CU at
// 14 GB/s = 5.9 B/cy vs 24.6 GB/s fair share. Little's law back-solve:
// ~5 outstanding global_load_lds per WAVE (shallow per-wave DMA queue),
// so one staging wave can never go faster regardless of architected depth.
//
// Fix this round: STAGING PARALLELIZED ACROSS ALL 4 WAVES. Wave w stages
// rows [4w, 4w+4) of each 16-row chunk (4 gload_lds per wave per chunk,
// depth-3 pipeline = 12 outstanding per wave across 4 independent DMA
// queues => ~4x per-CU in-flight, enough to reach the HBM fair share).
// Sync per chunk: each wave waits ITS own counted vmcnt (8 = chunks
// c+2,c+3 still flying; never drained to 0 in the main loop), then one
// s_barrier publishes chunk c+1. Consumer gathers via alias-opaque asm
// ds_read_b32 with immediate offsets + lgkm fence (rule #18).
// WAR: STAGE(c+3) targets buffer (c-1)%4, whose asm reads were
// lgkm-drained before the previous barrier.
//
// Prediction: kernel 37 -> 21-24us (HBM-bound), dur_us 177-182. If
// unchanged => per-CU (not per-wave) DMA cap; next step = plain-gather
// multi-wave producers.

constexpr int B = 256, T = 512, C = 256, U = 64;
constexpr int CH = 16;   // time-steps per chunk
constexpr int NBUF = 4;  // LDS chunk ring (64 KB)
#define EPSF 1e-7f

__device__ __forceinline__ float dpp_wave_shr1(float x) {
    // alpha[2l-1]: previous lane's a_odd; lane 0 gets 0 (bound_ctrl).
    return __int_as_float(__builtin_amdgcn_update_dpp(
        0, __float_as_int(x), 0x138, 0xf, 0xf, true));
}

#define DPPMAX(ctrl)                                                      \
    {                                                                     \
        float x_ = __int_as_float(__builtin_amdgcn_update_dpp(            \
            0, __float_as_int(m_), (ctrl), 0xf, 0xf, true));              \
        m_ = fmaxf(m_, x_);                                               \
    }

#define RESCALE()                                                         \
    {                                                                     \
        float m_ = fmaxf(fmaxf(a_even, a_odd), a_top);                    \
        DPPMAX(0x111) DPPMAX(0x112) DPPMAX(0x114) DPPMAX(0x118)           \
        DPPMAX(0x142) DPPMAX(0x143)                                       \
        const float mx_ = __int_as_float(                                 \
            __builtin_amdgcn_readlane(__float_as_int(m_), 63));           \
        int e_ = (__float_as_int(mx_) >> 23) & 0xff;                      \
        int k_ = 187 - e_;                                                \
        k_ = k_ > 127 ? 127 : k_;                                         \
        const float s_ = __int_as_float((k_ + 127) << 23);                \
        a_even *= s_; a_odd *= s_; a_top *= s_;                           \
        esum += k_;                                                       \
    }

// Wave wid stages its 4 rows (i = 4*wid .. 4*wid+3) of chunk cc into
// rows[cc % NBUF]. One coalesced global_load_lds dwordx4 per row
// (per-lane global src, wave-uniform LDS dest -> linear 1 KB row copy).
#define STAGE_W(cc)                                                        \
    {                                                                      \
        const int cs_ = (cc);                                              \
        float* lbase_ = &rows[cs_ % NBUF][0][0];                           \
        _Pragma("unroll")                                                  \
        for (int j = 0; j < 4; ++j) {                                      \
            const int i = rbase + j;                                       \
            int t = 1 + cs_ * CH + i;                                      \
            t = t < T ? t : T - 1;                                         \
            const float* g_ = rowp + (size_t)t * C + (lane << 2);          \
            __builtin_amdgcn_global_load_lds(                              \
                (const __attribute__((address_space(1))) void*)g_,         \
                (__attribute__((address_space(3))) void*)(lbase_ + i * C), \
                16, 0, 0);                                                 \
        }                                                                  \
    }

// One ds_read_b32 with a compile-time literal byte offset (row stride 1KB).
#define DSR(dst, addr, OS)                                                 \
    asm volatile("ds_read_b32 %0, %1 offset:" OS                           \
                 : "=v"(dst) : "v"(addr));

// Consumer: issue chunk cc's 32 LDS gathers (labels per-lane, blank bcast).
#define LDS_ISSUE(cc)                                                      \
    {                                                                      \
        const int cr_ = (cc);                                              \
        float(*row_)[C] = rows[cr_ % NBUF];                                \
        const unsigned labA_ = (unsigned)(size_t)                          \
            (__attribute__((address_space(3))) void*)&row_[0][label];      \
        const unsigned blkA_ = (unsigned)(size_t)                          \
            (__attribute__((address_space(3))) void*)&row_[0][C - 1];      \
        DSR(lab[0],  labA_, "0")     DSR(lab[1],  labA_, "1024")           \
        DSR(lab[2],  labA_, "2048")  DSR(lab[3],  labA_, "3072")           \
        DSR(lab[4],  labA_, "4096")  DSR(lab[5],  labA_, "5120")           \
        DSR(lab[6],  labA_, "6144")  DSR(lab[7],  labA_, "7168")           \
        DSR(lab[8],  labA_, "8192")  DSR(lab[9],  labA_, "9216")           \
        DSR(lab[10], labA_, "10240") DSR(lab[11], labA_, "11264")          \
        DSR(lab[12], labA_, "12288") DSR(lab[13], labA_, "13312")          \
        DSR(lab[14], labA_, "14336") DSR(lab[15], labA_, "15360")          \
        DSR(blk[0],  blkA_, "0")     DSR(blk[1],  blkA_, "1024")           \
        DSR(blk[2],  blkA_, "2048")  DSR(blk[3],  blkA_, "3072")           \
        DSR(blk[4],  blkA_, "4096")  DSR(blk[5],  blkA_, "5120")           \
        DSR(blk[6],  blkA_, "6144")  DSR(blk[7],  blkA_, "7168")           \
        DSR(blk[8],  blkA_, "8192")  DSR(blk[9],  blkA_, "9216")           \
        DSR(blk[10], blkA_, "10240") DSR(blk[11], blkA_, "11264")          \
        DSR(blk[12], blkA_, "12288") DSR(blk[13], blkA_, "13312")          \
        DSR(blk[14], blkA_, "14336") DSR(blk[15], blkA_, "15360")          \
    }

#define LGKM_FENCE()                                                       \
    asm volatile("s_waitcnt lgkmcnt(0)" ::: "memory");                     \
    __builtin_amdgcn_sched_barrier(0);

// NSTEPS recurrence steps. t = 1 + cc*CH + i; (t & 7) == 0 iff
// ((1 + i) & 7) == 0 (CH multiple of 8) -- compile-time cadence.
#define COMP_CHUNK(NSTEPS)                                                 \
    {                                                                      \
        _Pragma("unroll")                                                  \
        for (int i = 0; i < (NSTEPS); ++i) {                               \
            const float pb = blk[i] + EPSF;                                \
            const float pl = lab[i] + EPSF;                                \
            const float po = dpp_wave_shr1(a_odd);                         \
            const float skp = skip_ok ? po : 0.f;                          \
            const float ne = (a_even + po) * pb;                           \
            const float no = (a_odd + a_even + skp) * pl;                  \
            const float nt = (a_top + a_odd) * pb;                         \
            a_even = ne; a_odd = no; a_top = nt;                           \
            if (((1 + i) & 7) == 0) RESCALE();                             \
        }                                                                  \
    }

__global__ __launch_bounds__(256) void ctc_kernel(const int* __restrict__ y_true,
                                                  const float* __restrict__ y_pred,
                                                  float* __restrict__ out) {
    __shared__ float rows[NBUF][CH][C];  // 4 * 16 * 1KB = 64 KB ring
    const int b = blockIdx.x;
    const int tid = threadIdx.x;
    const int lane = tid & 63;
    const int wid = tid >> 6;
    const int rbase = wid << 2;  // this wave's 4 rows of each chunk
    const float* __restrict__ rowp = y_pred + (size_t)b * (T * C);

    // Consumer-only state (registers exist in all waves, used by wave 0).
    const int label = y_true[b * U + lane];
    bool skip_ok = false;
    float a_even = 0.f, a_odd = 0.f, a_top = 0.f;
    int esum = 0;  // stored = true * 2^esum
    float lab[CH], blk[CH];

    if (wid == 0) {
        const int label_prev = __shfl_up(label, 1);
        skip_ok = (lane > 0) && (label != label_prev);
        // t = 0 init (linear domain; unreachable states = 0).
        const float pb = rowp[C - 1] + EPSF;
        const float pl = rowp[label] + EPSF;
        a_even = (lane == 0) ? pb : 0.f;
        a_odd  = (lane == 0) ? pl : 0.f;
        a_top  = 0.f;
    }
    // Drain init loads so staging vmcnt bookkeeping is exact on all waves.
    asm volatile("s_waitcnt vmcnt(0)" ::: "memory");

    // Prologue: every wave stages its quarter of chunks 0,1,2
    // (12 instructions outstanding per wave).
    STAGE_W(0);
    STAGE_W(1);
    STAGE_W(2);
    // Own chunk-0 rows landed (chunks 1,2 = 8 still flying), then publish.
    asm volatile("s_waitcnt vmcnt(8)" ::: "memory");
    __builtin_amdgcn_sched_barrier(0);
    __builtin_amdgcn_s_barrier();

    // Main loop c = 0..28. Invariant entering iteration c: chunk c fully
    // in LDS (every wave vmcnt-verified its quarter before the barrier);
    // chunks c+1, c+2 in flight (8 per wave).
    for (int c = 0; c < 29; ++c) {
        if (wid == 0) { LDS_ISSUE(c); }
        __builtin_amdgcn_sched_barrier(0);
        STAGE_W(c + 3);  // all waves; targets buffer (c-1)%4 (reads drained)
        if (wid == 0) {
            LGKM_FENCE();
            COMP_CHUNK(CH);
        }
        // Own chunk-(c+1) rows done; c+2, c+3 (8) keep flying.
        asm volatile("s_waitcnt vmcnt(8)" ::: "memory");
        __builtin_amdgcn_sched_barrier(0);
        __builtin_amdgcn_s_barrier();
    }
    // c = 29: no staging left. Outstanding {30,31}=8 -> wait 4 => 30 done.
    if (wid == 0) { LDS_ISSUE(29); LGKM_FENCE(); COMP_CHUNK(CH); }
    asm volatile("s_waitcnt vmcnt(4)" ::: "memory");
    __builtin_amdgcn_sched_barrier(0);
    __builtin_amdgcn_s_barrier();
    // c = 30. Outstanding {31}=4 -> wait 0 => 31 done.
    if (wid == 0) { LDS_ISSUE(30); LGKM_FENCE(); COMP_CHUNK(CH); }
    asm volatile("s_waitcnt vmcnt(0)" ::: "memory");
    __builtin_amdgcn_sched_barrier(0);
    __builtin_amdgcn_s_barrier();
    // c = 31: t = 497..511 -> 15 steps; consumer only.
    if (wid == 0) {
        LDS_ISSUE(31);
        LGKM_FENCE();
        COMP_CHUNK(CH - 1);
        // loss = -ln(alpha[128] + alpha[127]); true = stored * 2^-esum
        if (lane == 63)
            out[b] = -logf(a_top + a_odd) + (float)esum * 0.69314718055994531f;
    }
}

extern "C" void kernel_launch(void* const* d_in, const int* in_sizes, int n_in,
                              void* d_out, int out_size, void* d_ws, size_t ws_size,
                              hipStream_t stream) {
    const int* y_true   = (const int*)d_in[0];
    const float* y_pred = (const float*)d_in[1];
    float* out = (float*)d_out;
    hipLaunchKernelGGL(ctc_kernel, dim3(B), dim3(256), 0, stream,
                       y_true, y_pred, out);
}